// Round 1
// baseline (33.593 us; speedup 1.0000x reference)
//
#include <hip/hip_runtime.h>
#include <hip/hip_bf16.h>

#define BB   4
#define CC   128
#define HH   192
#define WWd  192
#define HWp  (HH*WWd)      // 36864
#define OO   128
#define KK   7
#define NPIX (BB*HWp)      // 147456
#define TILE 64
#define XT_PITCH 136       // bf16 elems; 272 B rows, 16B-aligned

typedef short bf16x8 __attribute__((ext_vector_type(8)));
typedef float f32x4  __attribute__((ext_vector_type(4)));

static __device__ __forceinline__ unsigned short f2bf(float f) {
    union { __hip_bfloat16 h; unsigned short u; } cvt;
    cvt.h = __float2bfloat16(f);
    return cvt.u;
}
static __device__ __forceinline__ float bf2f(unsigned short u) {
    unsigned int v = ((unsigned int)u) << 16;
    return __uint_as_float(v);
}

// ---- prep: Wsum[o][c] = sum_k kernel_w[o*7+k, c] -> bf16 in MFMA A-frag order;
//      bsum[o] = sum_k kernel_b[o*7+k] (fp32)
__global__ __launch_bounds__(256) void prep_kernel(const float* __restrict__ kw,
                                                   const float* __restrict__ kb,
                                                   unsigned short* __restrict__ wfrag,
                                                   float* __restrict__ bsum) {
    int tid = blockIdx.x * 256 + threadIdx.x;   // 0..16383
    int o = tid >> 7, c = tid & 127;
    float s = 0.f;
#pragma unroll
    for (int k = 0; k < KK; ++k) s += kw[(o*KK + k)*CC + c];
    // main kernel reads: afrag[mt][ks] lane l elem j  <->  o = w*32+mt*16+(l&15), c = ks*32+(l>>4)*8+j
    int wv = o >> 5, mt = (o >> 4) & 1, lo = o & 15;
    int ks = c >> 5, g = (c >> 3) & 3, j = c & 7;
    int idx = ((((wv*2 + mt)*4 + ks)*64) + (lo + 16*g))*8 + j;
    wfrag[idx] = f2bf(s);
    if (c == 0) {
        float bs = 0.f;
#pragma unroll
        for (int k = 0; k < KK; ++k) bs += kb[o*KK + k];
        bsum[o] = bs;
    }
}

// ---- main: per block 64 pixels x all 128 outputs.
// out[p,o] = s[p] * (sum_c x[c,p]*Wsum[o,c] + bsum[o])
__global__ __launch_bounds__(256, 4) void conv_kernel(const float* __restrict__ x,
                                                      const unsigned short* __restrict__ wfrag,
                                                      const float* __restrict__ bsum,
                                                      float* __restrict__ out) {
    __shared__ unsigned short xc[CC][TILE];                    // 16 KB  [c][pix]
    __shared__ __align__(16) unsigned short xT[TILE][XT_PITCH];// 17408 B [pix][c]
    __shared__ float sPart[4][TILE];                           // 1 KB

    const int t = threadIdx.x;
    const int w = t >> 6;      // wave id: owns o in [w*32, w*32+32)
    const int l = t & 63;

    const int pixBase = blockIdx.x * TILE;
    const int bIdx   = pixBase / HWp;
    const int hwBase = pixBase - bIdx * HWp;     // multiple of 64
    const float* xb = x + (size_t)bIdx * CC * HWp + hwBase;

    // A-fragments (Wsum), hoisted: 2 m-tiles x 4 k-steps, one dwordx4 per lane each
    bf16x8 afrag[2][4];
#pragma unroll
    for (int mt = 0; mt < 2; ++mt)
#pragma unroll
        for (int ks = 0; ks < 4; ++ks)
            afrag[mt][ks] = *reinterpret_cast<const bf16x8*>(
                wfrag + ((((w*2 + mt)*4 + ks)*64) + l)*8);

    // Stage A: coalesced fp32 loads -> bf16 -> xc[c][pix]
    {
        const int p4 = (l & 15) * 4;   // 4 consecutive pixels
        const int cg = l >> 4;
#pragma unroll
        for (int it = 0; it < 8; ++it) {
            const int c = it*16 + w*4 + cg;
            const float4 v = *reinterpret_cast<const float4*>(xb + (size_t)c * HWp + p4);
            uint2 u;
            u.x = (unsigned int)f2bf(v.x) | ((unsigned int)f2bf(v.y) << 16);
            u.y = (unsigned int)f2bf(v.z) | ((unsigned int)f2bf(v.w) << 16);
            *reinterpret_cast<uint2*>(&xc[c][p4]) = u;
        }
    }
    __syncthreads();

    // Stage B: transpose xc -> xT[pix][c] (b128 writes), fp32 partial channel-sums
    {
        const int p = l;       // pixel
        const int q = w;       // c-quarter (32 channels)
        float part = 0.f;
#pragma unroll
        for (int i = 0; i < 4; ++i) {
            unsigned short e[8];
#pragma unroll
            for (int jj = 0; jj < 8; ++jj) {
                e[jj] = xc[q*32 + i*8 + jj][p];
                part += bf2f(e[jj]);
            }
            uint4 pk;
            pk.x = e[0] | ((unsigned int)e[1] << 16);
            pk.y = e[2] | ((unsigned int)e[3] << 16);
            pk.z = e[4] | ((unsigned int)e[5] << 16);
            pk.w = e[6] | ((unsigned int)e[7] << 16);
            *reinterpret_cast<uint4*>(&xT[p][q*32 + i*8]) = pk;
        }
        sPart[q][p] = part;
    }
    __syncthreads();

    // Stage C: MFMA. A=Wsum [o x c], B=xT^T [c x pix], D[o][pix]
    f32x4 acc[2][4];
#pragma unroll
    for (int mt = 0; mt < 2; ++mt)
#pragma unroll
        for (int nt = 0; nt < 4; ++nt)
            acc[mt][nt] = (f32x4){0.f, 0.f, 0.f, 0.f};

    const int lo16 = l & 15;
    const int g4   = l >> 4;
#pragma unroll
    for (int ks = 0; ks < 4; ++ks) {
        bf16x8 bfr[4];
#pragma unroll
        for (int nt = 0; nt < 4; ++nt)  // B-frag: lane: n = pix = lo16 (+16*nt), k = 8 contiguous c
            bfr[nt] = *reinterpret_cast<const bf16x8*>(&xT[nt*16 + lo16][ks*32 + g4*8]);
#pragma unroll
        for (int mt = 0; mt < 2; ++mt)
#pragma unroll
            for (int nt = 0; nt < 4; ++nt)
                acc[mt][nt] = __builtin_amdgcn_mfma_f32_16x16x32_bf16(
                    afrag[mt][ks], bfr[nt], acc[mt][nt], 0, 0, 0);
    }

    // Epilogue: D row = o = (l>>4)*4 + r (+tile base), col = pix = l&15 (+nt*16)
    float* ob = out + (size_t)bIdx * OO * HWp + hwBase + lo16;
#pragma unroll
    for (int nt = 0; nt < 4; ++nt) {
        const int pp = nt*16 + lo16;
        const float sv = sPart[0][pp] + sPart[1][pp] + sPart[2][pp] + sPart[3][pp];
#pragma unroll
        for (int mt = 0; mt < 2; ++mt) {
            const int o0 = w*32 + mt*16 + g4*4;
            const float4 bs4 = *reinterpret_cast<const float4*>(bsum + o0);
#pragma unroll
            for (int r = 0; r < 4; ++r) {
                const float bsv = (r == 0) ? bs4.x : (r == 1) ? bs4.y : (r == 2) ? bs4.z : bs4.w;
                ob[(size_t)(o0 + r) * HWp + nt*16] = (acc[mt][nt][r] + bsv) * sv;
            }
        }
    }
}

extern "C" void kernel_launch(void* const* d_in, const int* in_sizes, int n_in,
                              void* d_out, int out_size, void* d_ws, size_t ws_size,
                              hipStream_t stream) {
    const float* x  = (const float*)d_in[0];
    // d_in[1] offsets, d_in[2] tumor_center: mathematically dead (grid_sample on 1x1 input)
    const float* kw = (const float*)d_in[3];
    const float* kb = (const float*)d_in[4];
    float* outp = (float*)d_out;

    unsigned short* wfrag = (unsigned short*)d_ws;                 // 128*128 bf16 = 32 KB
    float* bsum = (float*)((char*)d_ws + 32768);                   // 128 f32

    prep_kernel<<<dim3(64), dim3(256), 0, stream>>>(kw, kb, wfrag, bsum);
    conv_kernel<<<dim3(NPIX / TILE), dim3(256), 0, stream>>>(x, wfrag, bsum, outp);
}